// Round 1
// baseline (1126.610 us; speedup 1.0000x reference)
//
#include <hip/hip_runtime.h>

#define SDIM 1024
#define BATCH 256

__global__ __launch_bounds__(256) void loss_kernel(const float* __restrict__ y_predict,
                                                   const int* __restrict__ gt_pos,
                                                   float* __restrict__ out) {
    const int b = threadIdx.x;           // 0..255, one batch per thread
    const int g0 = gt_pos[2 * b];
    const int g1 = gt_pos[2 * b + 1];

    // ---- block-wide sums: Sg0=Σg0, Sg1=Σg1, Sq=Σ(g0²+g1²) ----
    __shared__ int s_red[4][4];
    int v0 = g0, v1 = g1, v2 = g0 * g0, v3 = g1 * g1;
    #pragma unroll
    for (int off = 32; off > 0; off >>= 1) {
        v0 += __shfl_down(v0, off, 64);
        v1 += __shfl_down(v1, off, 64);
        v2 += __shfl_down(v2, off, 64);
        v3 += __shfl_down(v3, off, 64);
    }
    const int wave = threadIdx.x >> 6;
    const int lane = threadIdx.x & 63;
    if (lane == 0) {
        s_red[wave][0] = v0; s_red[wave][1] = v1;
        s_red[wave][2] = v2; s_red[wave][3] = v3;
    }
    __syncthreads();
    const int Sg0 = s_red[0][0] + s_red[1][0] + s_red[2][0] + s_red[3][0];
    const int Sg1 = s_red[0][1] + s_red[1][1] + s_red[2][1] + s_red[3][1];
    const int Sq  = s_red[0][2] + s_red[1][2] + s_red[2][2] + s_red[3][2]
                  + s_red[0][3] + s_red[1][3] + s_red[2][3] + s_red[3][3];

    // ---- issue all 36 gathers up-front (independent loads overlap) ----
    float yh[36];
    bool vld[36];
    long long sqv[36];
    const float* base = y_predict + ((size_t)b << 20);   // b * S * S
    #pragma unroll
    for (int o = 0; o < 36; ++o) {
        const int di = o / 6 - 3, dj = o % 6 - 3;
        const int p0 = g0 + di, p1 = g1 + dj;
        vld[o] = ((unsigned)p0 < (unsigned)SDIM) && ((unsigned)p1 < (unsigned)SDIM);
        const int c0 = min(max(p0, 0), SDIM - 1);
        const int c1 = min(max(p1, 0), SDIM - 1);
        yh[o] = base[(c0 << 10) + c1];
        // sq = B*(p0²+p1²) - 2*(p0*Sg0 + p1*Sg1) + Σ(g0²+g1²)   (exact integers)
        const long long a  = (long long)BATCH * (long long)(p0 * p0 + p1 * p1);
        const long long bq = 2LL * ((long long)p0 * Sg0 + (long long)p1 * Sg1);
        sqv[o] = a - bq + (long long)Sq;
    }

    // ---- per-thread term accumulation ----
    float sum = 0.0f;
    int cnt = 0;
    #pragma unroll
    for (int o = 0; o < 36; ++o) {
        if (!vld[o]) continue;
        const float sqf = (float)sqv[o];
        const float y = expf(-sqf / 5.0f);      // underflows to 0 for real inputs
        const float d = yh[o] - y;
        float t;
        if (y == 1.0f) {
            t = -logf(yh[o]) * d * d;
        } else {
            const float om = 1.0f - y;
            const float om2 = om * om;
            t = -logf(1.0f - yh[o]) * om2 * om2 * d * d;
        }
        sum += t;
        cnt += 1;
    }

    // ---- block reduction of (sum, cnt) ----
    #pragma unroll
    for (int off = 32; off > 0; off >>= 1) {
        sum += __shfl_down(sum, off, 64);
        cnt += __shfl_down(cnt, off, 64);
    }
    __shared__ float s_sum[4];
    __shared__ int   s_cnt[4];
    if (lane == 0) { s_sum[wave] = sum; s_cnt[wave] = cnt; }
    __syncthreads();
    if (threadIdx.x == 0) {
        const float ts = s_sum[0] + s_sum[1] + s_sum[2] + s_sum[3];
        const int   tc = s_cnt[0] + s_cnt[1] + s_cnt[2] + s_cnt[3];
        out[0] = ts / (float)tc;
    }
}

extern "C" void kernel_launch(void* const* d_in, const int* in_sizes, int n_in,
                              void* d_out, int out_size, void* d_ws, size_t ws_size,
                              hipStream_t stream) {
    const float* y_predict = (const float*)d_in[0];
    const int*   gt_pos    = (const int*)d_in[1];
    float*       out       = (float*)d_out;
    loss_kernel<<<1, 256, 0, stream>>>(y_predict, gt_pos, out);
}